// Round 1
// baseline (661.141 us; speedup 1.0000x reference)
//
#include <hip/hip_runtime.h>
#include <math.h>
#include <stddef.h>

#define N224 224
#define PIX 50176   // 224*224

// ---------------- DFT stage 1: Cx = C @ x, Sx = S @ x (48 images) -----------
// grid (7,7,48), block (16,16). 32x32 output tile, 2x2 per-thread micro-tile.
__global__ __launch_bounds__(256) void dft_stage1(
    const float* __restrict__ seq, const float* __restrict__ Cm,
    const float* __restrict__ Sm, float* __restrict__ Cx, float* __restrict__ Sx)
{
  const int p = blockIdx.z;             // image index = b*3 + c
  const int b = p / 3, ch = p % 3;
  const float* __restrict__ x = seq + ((((size_t)b * 8 + 4) * 3 + ch) * PIX);
  const int i0 = blockIdx.y * 32, k0 = blockIdx.x * 32;
  const int tx = threadIdx.x, ty = threadIdx.y;
  __shared__ float Ct[32][17], St[32][17], Xt[16][33];
  float aC00=0,aC01=0,aC10=0,aC11=0, aS00=0,aS01=0,aS10=0,aS11=0;
  for (int jt = 0; jt < 14; ++jt) {
    const int j = jt * 16;
    Ct[ty][tx]      = Cm[(i0+ty)*N224 + j+tx];
    Ct[ty+16][tx]   = Cm[(i0+ty+16)*N224 + j+tx];
    St[ty][tx]      = Sm[(i0+ty)*N224 + j+tx];
    St[ty+16][tx]   = Sm[(i0+ty+16)*N224 + j+tx];
    Xt[ty][tx]      = x[(j+ty)*N224 + k0+tx];
    Xt[ty][tx+16]   = x[(j+ty)*N224 + k0+tx+16];
    __syncthreads();
#pragma unroll
    for (int jj = 0; jj < 16; ++jj) {
      const float c0 = Ct[ty][jj],    c1 = Ct[ty+16][jj];
      const float s0 = St[ty][jj],    s1 = St[ty+16][jj];
      const float x0 = Xt[jj][tx],    x1 = Xt[jj][tx+16];
      aC00 = fmaf(c0, x0, aC00);  aC01 = fmaf(c0, x1, aC01);
      aC10 = fmaf(c1, x0, aC10);  aC11 = fmaf(c1, x1, aC11);
      aS00 = fmaf(s0, x0, aS00);  aS01 = fmaf(s0, x1, aS01);
      aS10 = fmaf(s1, x0, aS10);  aS11 = fmaf(s1, x1, aS11);
    }
    __syncthreads();
  }
  const size_t base = (size_t)p * PIX;
  Cx[base + (i0+ty   )*N224 + k0+tx   ] = aC00;
  Cx[base + (i0+ty   )*N224 + k0+tx+16] = aC01;
  Cx[base + (i0+ty+16)*N224 + k0+tx   ] = aC10;
  Cx[base + (i0+ty+16)*N224 + k0+tx+16] = aC11;
  Sx[base + (i0+ty   )*N224 + k0+tx   ] = aS00;
  Sx[base + (i0+ty   )*N224 + k0+tx+16] = aS01;
  Sx[base + (i0+ty+16)*N224 + k0+tx   ] = aS10;
  Sx[base + (i0+ty+16)*N224 + k0+tx+16] = aS11;
}

// --------- DFT stage 2: re/im + log-magnitude + fftshift-on-write ----------
// re = Cx@C - Sx@S ; im' = Cx@S + Sx@C (sign dropped: only im^2 used)
__global__ __launch_bounds__(256) void dft_stage2(
    const float* __restrict__ Cx, const float* __restrict__ Sx,
    const float* __restrict__ Cm, const float* __restrict__ Sm,
    float* __restrict__ spec)
{
  const int p = blockIdx.z;
  const int i0 = blockIdx.y * 32, k0 = blockIdx.x * 32;
  const int tx = threadIdx.x, ty = threadIdx.y;
  const size_t base = (size_t)p * PIX;
  __shared__ float CxT[32][17], SxT[32][17], Ct[16][33], St[16][33];
  float re00=0,re01=0,re10=0,re11=0, im00=0,im01=0,im10=0,im11=0;
  for (int jt = 0; jt < 14; ++jt) {
    const int j = jt * 16;
    CxT[ty][tx]    = Cx[base + (i0+ty)*N224 + j+tx];
    CxT[ty+16][tx] = Cx[base + (i0+ty+16)*N224 + j+tx];
    SxT[ty][tx]    = Sx[base + (i0+ty)*N224 + j+tx];
    SxT[ty+16][tx] = Sx[base + (i0+ty+16)*N224 + j+tx];
    Ct[ty][tx]     = Cm[(j+ty)*N224 + k0+tx];
    Ct[ty][tx+16]  = Cm[(j+ty)*N224 + k0+tx+16];
    St[ty][tx]     = Sm[(j+ty)*N224 + k0+tx];
    St[ty][tx+16]  = Sm[(j+ty)*N224 + k0+tx+16];
    __syncthreads();
#pragma unroll
    for (int jj = 0; jj < 16; ++jj) {
      const float cx0 = CxT[ty][jj],    cx1 = CxT[ty+16][jj];
      const float sx0 = SxT[ty][jj],    sx1 = SxT[ty+16][jj];
      const float c0  = Ct[jj][tx],     c1  = Ct[jj][tx+16];
      const float s0  = St[jj][tx],     s1  = St[jj][tx+16];
      re00 = fmaf(cx0, c0, re00); re00 = fmaf(-sx0, s0, re00);
      re01 = fmaf(cx0, c1, re01); re01 = fmaf(-sx0, s1, re01);
      re10 = fmaf(cx1, c0, re10); re10 = fmaf(-sx1, s0, re10);
      re11 = fmaf(cx1, c1, re11); re11 = fmaf(-sx1, s1, re11);
      im00 = fmaf(cx0, s0, im00); im00 = fmaf(sx0, c0, im00);
      im01 = fmaf(cx0, s1, im01); im01 = fmaf(sx0, c1, im01);
      im10 = fmaf(cx1, s0, im10); im10 = fmaf(sx1, c0, im10);
      im11 = fmaf(cx1, s1, im11); im11 = fmaf(sx1, c1, im11);
    }
    __syncthreads();
  }
#pragma unroll
  for (int a = 0; a < 2; ++a) {
#pragma unroll
    for (int d = 0; d < 2; ++d) {
      const int i = i0 + ty + a*16, k = k0 + tx + d*16;
      float re, im;
      if (a == 0 && d == 0) { re = re00; im = im00; }
      else if (a == 0)      { re = re01; im = im01; }
      else if (d == 0)      { re = re10; im = im10; }
      else                  { re = re11; im = im11; }
      const float mag = sqrtf(fmaf(re, re, fmaf(im, im, 1e-8f)));
      const float sp  = logf(mag + 1e-8f);
      const int oi = (i < 112) ? i + 112 : i - 112;
      const int ok = (k < 112) ? k + 112 : k - 112;
      spec[base + oi*N224 + ok] = sp;
    }
  }
}

// ----------------- conv1 (3->16, 3x3 SAME) + BN + ReLU + 2x2 maxpool --------
// out (16,16,112,112); idx=((b*16+co)*112+py)*112+px; 12544 blocks x 256
// (112*112 = 49*256 so co is block-uniform)
__global__ __launch_bounds__(256) void conv1_pool(
    const float* __restrict__ spec, const float* __restrict__ w,
    const float* __restrict__ cb, const float* __restrict__ g,
    const float* __restrict__ be, const float* __restrict__ mm,
    const float* __restrict__ vv, float* __restrict__ out)
{
  const int tid = threadIdx.x;
  const int idx = blockIdx.x * 256 + tid;
  const int px = idx % 112;
  int t = idx / 112;
  const int py = t % 112; t /= 112;
  const int co = t % 16;
  const int b  = t / 16;
  __shared__ float ws[27];
  if (tid < 27) ws[tid] = w[co*27 + tid];
  __syncthreads();
  const float s  = g[co] * rsqrtf(vv[co] + 1e-5f);
  const float sh = be[co] - mm[co]*s;
  const float bb = cb[co];
  float a00=0, a01=0, a10=0, a11=0;
  const int oy0 = 2*py - 1, ox0 = 2*px - 1;
  for (int ci = 0; ci < 3; ++ci) {
    const float* __restrict__ ip = spec + ((size_t)b*3 + ci) * PIX;
    float patch[4][4];
#pragma unroll
    for (int r = 0; r < 4; ++r) {
      const int y = oy0 + r;
      const bool yok = (y >= 0) && (y < 224);
#pragma unroll
      for (int cc = 0; cc < 4; ++cc) {
        const int xx = ox0 + cc;
        patch[r][cc] = (yok && xx >= 0 && xx < 224) ? ip[y*N224 + xx] : 0.f;
      }
    }
    const float* wc = ws + ci*9;
#pragma unroll
    for (int ky = 0; ky < 3; ++ky)
#pragma unroll
      for (int kx = 0; kx < 3; ++kx) {
        const float wv = wc[ky*3 + kx];
        a00 = fmaf(patch[ky  ][kx  ], wv, a00);
        a01 = fmaf(patch[ky  ][kx+1], wv, a01);
        a10 = fmaf(patch[ky+1][kx  ], wv, a10);
        a11 = fmaf(patch[ky+1][kx+1], wv, a11);
      }
  }
  const float v0 = (a00 + bb)*s + sh, v1 = (a01 + bb)*s + sh;
  const float v2 = (a10 + bb)*s + sh, v3 = (a11 + bb)*s + sh;
  out[idx] = fmaxf(fmaxf(fmaxf(v0, v1), fmaxf(v2, v3)), 0.f);
}

// ----------------- conv2 (16->32, 3x3 SAME) + BN + ReLU + 2x2 maxpool -------
// grid (13, 512): blockIdx.y = b*32+co (uniform), 13*256 covers 56*56=3136
__global__ __launch_bounds__(256) void conv2_pool(
    const float* __restrict__ h1, const float* __restrict__ w,
    const float* __restrict__ cb, const float* __restrict__ g,
    const float* __restrict__ be, const float* __restrict__ mm,
    const float* __restrict__ vv, float* __restrict__ out)
{
  const int tid = threadIdx.x;
  const int bc = blockIdx.y;
  const int co = bc % 32, b = bc / 32;
  __shared__ float ws[144];
  for (int i = tid; i < 144; i += 256) ws[i] = w[co*144 + i];
  __syncthreads();
  const int pix = blockIdx.x * 256 + tid;
  if (pix >= 3136) return;
  const int px = pix % 56, py = pix / 56;
  const float s  = g[co] * rsqrtf(vv[co] + 1e-5f);
  const float sh = be[co] - mm[co]*s;
  const float bb = cb[co];
  float a00=0, a01=0, a10=0, a11=0;
  const int oy0 = 2*py - 1, ox0 = 2*px - 1;
  for (int ci = 0; ci < 16; ++ci) {
    const float* __restrict__ ip = h1 + ((size_t)b*16 + ci) * 12544; // 112*112
    float patch[4][4];
#pragma unroll
    for (int r = 0; r < 4; ++r) {
      const int y = oy0 + r;
      const bool yok = (y >= 0) && (y < 112);
#pragma unroll
      for (int cc = 0; cc < 4; ++cc) {
        const int xx = ox0 + cc;
        patch[r][cc] = (yok && xx >= 0 && xx < 112) ? ip[y*112 + xx] : 0.f;
      }
    }
    const float* wc = ws + ci*9;
#pragma unroll
    for (int ky = 0; ky < 3; ++ky)
#pragma unroll
      for (int kx = 0; kx < 3; ++kx) {
        const float wv = wc[ky*3 + kx];
        a00 = fmaf(patch[ky  ][kx  ], wv, a00);
        a01 = fmaf(patch[ky  ][kx+1], wv, a01);
        a10 = fmaf(patch[ky+1][kx  ], wv, a10);
        a11 = fmaf(patch[ky+1][kx+1], wv, a11);
      }
  }
  const float v0 = (a00 + bb)*s + sh, v1 = (a01 + bb)*s + sh;
  const float v2 = (a10 + bb)*s + sh, v3 = (a11 + bb)*s + sh;
  out[((size_t)bc*56 + py)*56 + px] =
      fmaxf(fmaxf(fmaxf(v0, v1), fmaxf(v2, v3)), 0.f);
}

// --------- conv3 (32->64, 3x3 SAME) + BN + ReLU + global mean ---------------
// one block per (b,co); 2x2 pixel blocks, 28*28=784 of them over 56x56
__global__ __launch_bounds__(256) void conv3_mean(
    const float* __restrict__ h2, const float* __restrict__ w,
    const float* __restrict__ cb, const float* __restrict__ g,
    const float* __restrict__ be, const float* __restrict__ mm,
    const float* __restrict__ vv, float* __restrict__ h3)
{
  const int bc = blockIdx.x;          // b*64 + co
  const int co = bc % 64, b = bc / 64;
  const int tid = threadIdx.x;
  __shared__ float ws[288];
  for (int i = tid; i < 288; i += 256) ws[i] = w[co*288 + i];
  __syncthreads();
  const float s  = g[co] * rsqrtf(vv[co] + 1e-5f);
  const float sh = be[co] - mm[co]*s;
  const float bb = cb[co];
  float sum = 0.f;
  for (int pb = tid; pb < 784; pb += 256) {
    const int py = (pb / 28) * 2, px = (pb % 28) * 2;
    float a00=0, a01=0, a10=0, a11=0;
    const int oy0 = py - 1, ox0 = px - 1;
    for (int ci = 0; ci < 32; ++ci) {
      const float* __restrict__ ip = h2 + ((size_t)b*32 + ci) * 3136; // 56*56
      float patch[4][4];
#pragma unroll
      for (int r = 0; r < 4; ++r) {
        const int y = oy0 + r;
        const bool yok = (y >= 0) && (y < 56);
#pragma unroll
        for (int cc = 0; cc < 4; ++cc) {
          const int xx = ox0 + cc;
          patch[r][cc] = (yok && xx >= 0 && xx < 56) ? ip[y*56 + xx] : 0.f;
        }
      }
      const float* wc = ws + ci*9;
#pragma unroll
      for (int ky = 0; ky < 3; ++ky)
#pragma unroll
        for (int kx = 0; kx < 3; ++kx) {
          const float wv = wc[ky*3 + kx];
          a00 = fmaf(patch[ky  ][kx  ], wv, a00);
          a01 = fmaf(patch[ky  ][kx+1], wv, a01);
          a10 = fmaf(patch[ky+1][kx  ], wv, a10);
          a11 = fmaf(patch[ky+1][kx+1], wv, a11);
        }
    }
    sum += fmaxf((a00 + bb)*s + sh, 0.f) + fmaxf((a01 + bb)*s + sh, 0.f)
         + fmaxf((a10 + bb)*s + sh, 0.f) + fmaxf((a11 + bb)*s + sh, 0.f);
  }
  __shared__ float red[256];
  red[tid] = sum;
  __syncthreads();
  for (int o = 128; o > 0; o >>= 1) {
    if (tid < o) red[tid] += red[tid + o];
    __syncthreads();
  }
  if (tid == 0) h3[bc] = red[0] * (1.0f / 3136.0f);
}

// ----------------------------- FC + ReLU ------------------------------------
__global__ __launch_bounds__(256) void fc_relu(
    const float* __restrict__ h3, const float* __restrict__ fw,
    const float* __restrict__ fb, float* __restrict__ out)
{
  const int idx = blockIdx.x * 256 + threadIdx.x;
  if (idx >= 16*128) return;
  const int o = idx % 128, b = idx / 128;
  float acc = fb[o];
#pragma unroll
  for (int c = 0; c < 64; ++c)
    acc = fmaf(h3[b*64 + c], fw[o*64 + c], acc);
  out[idx] = fmaxf(acc, 0.f);
}

extern "C" void kernel_launch(void* const* d_in, const int* in_sizes, int n_in,
                              void* d_out, int out_size, void* d_ws, size_t ws_size,
                              hipStream_t stream) {
  const float* seq  = (const float*)d_in[0];
  const float* dcos = (const float*)d_in[1];
  const float* dsin = (const float*)d_in[2];
  const float* c1w  = (const float*)d_in[3];
  const float* c1b  = (const float*)d_in[4];
  const float* b1g  = (const float*)d_in[5];
  const float* b1b  = (const float*)d_in[6];
  const float* b1m  = (const float*)d_in[7];
  const float* b1v  = (const float*)d_in[8];
  const float* c2w  = (const float*)d_in[9];
  const float* c2b  = (const float*)d_in[10];
  const float* b2g  = (const float*)d_in[11];
  const float* b2b  = (const float*)d_in[12];
  const float* b2m  = (const float*)d_in[13];
  const float* b2v  = (const float*)d_in[14];
  const float* c3w  = (const float*)d_in[15];
  const float* c3b  = (const float*)d_in[16];
  const float* b3g  = (const float*)d_in[17];
  const float* b3b  = (const float*)d_in[18];
  const float* b3m  = (const float*)d_in[19];
  const float* b3v  = (const float*)d_in[20];
  const float* fw   = (const float*)d_in[21];
  const float* fb   = (const float*)d_in[22];
  float* out = (float*)d_out;

  float* ws   = (float*)d_ws;
  float* Cx   = ws;               // 48*50176 = 2,408,448 floats
  float* Sx   = ws + 2408448;     // 2,408,448
  float* spec = ws + 4816896;     // 2,408,448
  float* h1   = ws;               // 3,211,264 (reuses dead Cx+Sx)
  float* h2   = ws + 4816896;     // 1,605,632 (reuses dead spec)
  float* h3   = ws + 7225344;     // 1024
  // total: ~28.9 MB of ws

  dim3 blk(16, 16);
  dim3 gdft(7, 7, 48);
  dft_stage1<<<gdft, blk, 0, stream>>>(seq, dcos, dsin, Cx, Sx);
  dft_stage2<<<gdft, blk, 0, stream>>>(Cx, Sx, dcos, dsin, spec);
  conv1_pool<<<12544, 256, 0, stream>>>(spec, c1w, c1b, b1g, b1b, b1m, b1v, h1);
  conv2_pool<<<dim3(13, 512), 256, 0, stream>>>(h1, c2w, c2b, b2g, b2b, b2m, b2v, h2);
  conv3_mean<<<1024, 256, 0, stream>>>(h2, c3w, c3b, b3g, b3b, b3m, b3v, h3);
  fc_relu<<<8, 256, 0, stream>>>(h3, fw, fb, out);
}

// Round 2
// 307.048 us; speedup vs baseline: 2.1532x; 2.1532x over previous
//
#include <hip/hip_runtime.h>
#include <math.h>
#include <stddef.h>

#define N224 224
#define PIX 50176   // 224*224

// ---------------- DFT stage 1: Cx = C @ x, Sx = S @ x (48 images) -----------
// grid (7,7,48), block (16,16). 32x32 output tile, 2x2 per-thread micro-tile.
__global__ __launch_bounds__(256) void dft_stage1(
    const float* __restrict__ seq, const float* __restrict__ Cm,
    const float* __restrict__ Sm, float* __restrict__ Cx, float* __restrict__ Sx)
{
  const int p = blockIdx.z;             // image index = b*3 + c
  const int b = p / 3, ch = p % 3;
  const float* __restrict__ x = seq + ((((size_t)b * 8 + 4) * 3 + ch) * PIX);
  const int i0 = blockIdx.y * 32, k0 = blockIdx.x * 32;
  const int tx = threadIdx.x, ty = threadIdx.y;
  __shared__ float Ct[32][17], St[32][17], Xt[16][33];
  float aC00=0,aC01=0,aC10=0,aC11=0, aS00=0,aS01=0,aS10=0,aS11=0;
  for (int jt = 0; jt < 14; ++jt) {
    const int j = jt * 16;
    Ct[ty][tx]      = Cm[(i0+ty)*N224 + j+tx];
    Ct[ty+16][tx]   = Cm[(i0+ty+16)*N224 + j+tx];
    St[ty][tx]      = Sm[(i0+ty)*N224 + j+tx];
    St[ty+16][tx]   = Sm[(i0+ty+16)*N224 + j+tx];
    Xt[ty][tx]      = x[(j+ty)*N224 + k0+tx];
    Xt[ty][tx+16]   = x[(j+ty)*N224 + k0+tx+16];
    __syncthreads();
#pragma unroll
    for (int jj = 0; jj < 16; ++jj) {
      const float c0 = Ct[ty][jj],    c1 = Ct[ty+16][jj];
      const float s0 = St[ty][jj],    s1 = St[ty+16][jj];
      const float x0 = Xt[jj][tx],    x1 = Xt[jj][tx+16];
      aC00 = fmaf(c0, x0, aC00);  aC01 = fmaf(c0, x1, aC01);
      aC10 = fmaf(c1, x0, aC10);  aC11 = fmaf(c1, x1, aC11);
      aS00 = fmaf(s0, x0, aS00);  aS01 = fmaf(s0, x1, aS01);
      aS10 = fmaf(s1, x0, aS10);  aS11 = fmaf(s1, x1, aS11);
    }
    __syncthreads();
  }
  const size_t base = (size_t)p * PIX;
  Cx[base + (i0+ty   )*N224 + k0+tx   ] = aC00;
  Cx[base + (i0+ty   )*N224 + k0+tx+16] = aC01;
  Cx[base + (i0+ty+16)*N224 + k0+tx   ] = aC10;
  Cx[base + (i0+ty+16)*N224 + k0+tx+16] = aC11;
  Sx[base + (i0+ty   )*N224 + k0+tx   ] = aS00;
  Sx[base + (i0+ty   )*N224 + k0+tx+16] = aS01;
  Sx[base + (i0+ty+16)*N224 + k0+tx   ] = aS10;
  Sx[base + (i0+ty+16)*N224 + k0+tx+16] = aS11;
}

// --------- DFT stage 2: re/im + log-magnitude + fftshift-on-write ----------
// re = Cx@C - Sx@S ; im' = Cx@S + Sx@C (sign dropped: only im^2 used)
__global__ __launch_bounds__(256) void dft_stage2(
    const float* __restrict__ Cx, const float* __restrict__ Sx,
    const float* __restrict__ Cm, const float* __restrict__ Sm,
    float* __restrict__ spec)
{
  const int p = blockIdx.z;
  const int i0 = blockIdx.y * 32, k0 = blockIdx.x * 32;
  const int tx = threadIdx.x, ty = threadIdx.y;
  const size_t base = (size_t)p * PIX;
  __shared__ float CxT[32][17], SxT[32][17], Ct[16][33], St[16][33];
  float re00=0,re01=0,re10=0,re11=0, im00=0,im01=0,im10=0,im11=0;
  for (int jt = 0; jt < 14; ++jt) {
    const int j = jt * 16;
    CxT[ty][tx]    = Cx[base + (i0+ty)*N224 + j+tx];
    CxT[ty+16][tx] = Cx[base + (i0+ty+16)*N224 + j+tx];
    SxT[ty][tx]    = Sx[base + (i0+ty)*N224 + j+tx];
    SxT[ty+16][tx] = Sx[base + (i0+ty+16)*N224 + j+tx];
    Ct[ty][tx]     = Cm[(j+ty)*N224 + k0+tx];
    Ct[ty][tx+16]  = Cm[(j+ty)*N224 + k0+tx+16];
    St[ty][tx]     = Sm[(j+ty)*N224 + k0+tx];
    St[ty][tx+16]  = Sm[(j+ty)*N224 + k0+tx+16];
    __syncthreads();
#pragma unroll
    for (int jj = 0; jj < 16; ++jj) {
      const float cx0 = CxT[ty][jj],    cx1 = CxT[ty+16][jj];
      const float sx0 = SxT[ty][jj],    sx1 = SxT[ty+16][jj];
      const float c0  = Ct[jj][tx],     c1  = Ct[jj][tx+16];
      const float s0  = St[jj][tx],     s1  = St[jj][tx+16];
      re00 = fmaf(cx0, c0, re00); re00 = fmaf(-sx0, s0, re00);
      re01 = fmaf(cx0, c1, re01); re01 = fmaf(-sx0, s1, re01);
      re10 = fmaf(cx1, c0, re10); re10 = fmaf(-sx1, s0, re10);
      re11 = fmaf(cx1, c1, re11); re11 = fmaf(-sx1, s1, re11);
      im00 = fmaf(cx0, s0, im00); im00 = fmaf(sx0, c0, im00);
      im01 = fmaf(cx0, s1, im01); im01 = fmaf(sx0, c1, im01);
      im10 = fmaf(cx1, s0, im10); im10 = fmaf(sx1, c0, im10);
      im11 = fmaf(cx1, s1, im11); im11 = fmaf(sx1, c1, im11);
    }
    __syncthreads();
  }
#pragma unroll
  for (int a = 0; a < 2; ++a) {
#pragma unroll
    for (int d = 0; d < 2; ++d) {
      const int i = i0 + ty + a*16, k = k0 + tx + d*16;
      float re, im;
      if (a == 0 && d == 0) { re = re00; im = im00; }
      else if (a == 0)      { re = re01; im = im01; }
      else if (d == 0)      { re = re10; im = im10; }
      else                  { re = re11; im = im11; }
      const float mag = sqrtf(fmaf(re, re, fmaf(im, im, 1e-8f)));
      const float sp  = logf(mag + 1e-8f);
      const int oi = (i < 112) ? i + 112 : i - 112;
      const int ok = (k < 112) ? k + 112 : k - 112;
      spec[base + oi*N224 + ok] = sp;
    }
  }
}

// ----------------- conv1 (3->16, 3x3 SAME) + BN + ReLU + 2x2 maxpool --------
__global__ __launch_bounds__(256) void conv1_pool(
    const float* __restrict__ spec, const float* __restrict__ w,
    const float* __restrict__ cb, const float* __restrict__ g,
    const float* __restrict__ be, const float* __restrict__ mm,
    const float* __restrict__ vv, float* __restrict__ out)
{
  const int tid = threadIdx.x;
  const int idx = blockIdx.x * 256 + tid;
  const int px = idx % 112;
  int t = idx / 112;
  const int py = t % 112; t /= 112;
  const int co = t % 16;
  const int b  = t / 16;
  __shared__ float ws[27];
  if (tid < 27) ws[tid] = w[co*27 + tid];
  __syncthreads();
  const float s  = g[co] * rsqrtf(vv[co] + 1e-5f);
  const float sh = be[co] - mm[co]*s;
  const float bb = cb[co];
  float a00=0, a01=0, a10=0, a11=0;
  const int oy0 = 2*py - 1, ox0 = 2*px - 1;
#pragma unroll
  for (int ci = 0; ci < 3; ++ci) {
    const float* __restrict__ ip = spec + ((size_t)b*3 + ci) * PIX;
    float patch[4][4];
#pragma unroll
    for (int r = 0; r < 4; ++r) {
      const int y = oy0 + r;
      const bool yok = (y >= 0) && (y < 224);
#pragma unroll
      for (int cc = 0; cc < 4; ++cc) {
        const int xx = ox0 + cc;
        patch[r][cc] = (yok && xx >= 0 && xx < 224) ? ip[y*N224 + xx] : 0.f;
      }
    }
    const float* wc = ws + ci*9;
#pragma unroll
    for (int ky = 0; ky < 3; ++ky)
#pragma unroll
      for (int kx = 0; kx < 3; ++kx) {
        const float wv = wc[ky*3 + kx];
        a00 = fmaf(patch[ky  ][kx  ], wv, a00);
        a01 = fmaf(patch[ky  ][kx+1], wv, a01);
        a10 = fmaf(patch[ky+1][kx  ], wv, a10);
        a11 = fmaf(patch[ky+1][kx+1], wv, a11);
      }
  }
  const float v0 = (a00 + bb)*s + sh, v1 = (a01 + bb)*s + sh;
  const float v2 = (a10 + bb)*s + sh, v3 = (a11 + bb)*s + sh;
  out[idx] = fmaxf(fmaxf(fmaxf(v0, v1), fmaxf(v2, v3)), 0.f);
}

// -------- conv2 (16->32) + BN + ReLU + 2x2 maxpool, LDS band version --------
// grid (28, 16): band of 2 pooled rows (= 4 conv rows, 6 input rows).
// 256 threads = 8 x-slices x 32 co. LDS: 8-ci chunks, weights [cc][k][co].
__global__ __launch_bounds__(256) void conv2_band(
    const float* __restrict__ h1, const float* __restrict__ w,
    const float* __restrict__ cb, const float* __restrict__ g,
    const float* __restrict__ be, const float* __restrict__ mm,
    const float* __restrict__ vv, float* __restrict__ out)
{
  const int band = blockIdx.x;     // 0..27
  const int b    = blockIdx.y;     // 0..15
  const int tid  = threadIdx.x;
  const int co   = tid & 31;
  const int q    = tid >> 5;       // 0..7, x-slice
  const int cy0  = band * 4;       // conv-row base
  __shared__ float in_t[8][6][114];
  __shared__ float wt[8][9][32];
  float acc[4][14];
#pragma unroll
  for (int i = 0; i < 4; ++i)
#pragma unroll
    for (int j = 0; j < 14; ++j) acc[i][j] = 0.f;

  for (int chunk = 0; chunk < 2; ++chunk) {
    const int ci0 = chunk * 8;
    __syncthreads();
    for (int i = tid; i < 8*6*112; i += 256) {
      const int x = i % 112, r = (i / 112) % 6, cc = i / 672;
      const int y = cy0 - 1 + r;
      float v = 0.f;
      if (y >= 0 && y < 112)
        v = h1[(((size_t)b*16 + ci0+cc)*112 + y)*112 + x];
      in_t[cc][r][x+1] = v;
    }
    if (tid < 48) { const int cc = tid / 6, r = tid % 6;
                    in_t[cc][r][0] = 0.f; in_t[cc][r][113] = 0.f; }
    for (int i = tid; i < 8*9*32; i += 256) {
      const int coi = i & 31, k = (i >> 5) % 9, cc = i / 288;
      wt[cc][k][coi] = w[coi*144 + (ci0+cc)*9 + k];
    }
    __syncthreads();
    const int x0 = q * 14;
    for (int cc = 0; cc < 8; ++cc) {
      float wr[9];
#pragma unroll
      for (int k = 0; k < 9; ++k) wr[k] = wt[cc][k][co];
#pragma unroll
      for (int rr = 0; rr < 6; ++rr) {
        float xr[16];
        const float2* rp = (const float2*)(&in_t[cc][rr][x0]);
#pragma unroll
        for (int t = 0; t < 8; ++t) { const float2 v = rp[t]; xr[2*t] = v.x; xr[2*t+1] = v.y; }
#pragma unroll
        for (int crow = 0; crow < 4; ++crow) {
          const int krow = rr - crow;
          if (krow < 0 || krow > 2) continue;
#pragma unroll
          for (int x = 0; x < 14; ++x) {
            acc[crow][x] = fmaf(xr[x  ], wr[krow*3  ], acc[crow][x]);
            acc[crow][x] = fmaf(xr[x+1], wr[krow*3+1], acc[crow][x]);
            acc[crow][x] = fmaf(xr[x+2], wr[krow*3+2], acc[crow][x]);
          }
        }
      }
    }
  }
  const float s  = g[co] * rsqrtf(vv[co] + 1e-5f);
  const float sh = be[co] - mm[co]*s;
  const float bb = cb[co];
  const int py0 = band * 2, px0 = q * 7;
#pragma unroll
  for (int pr = 0; pr < 2; ++pr)
#pragma unroll
    for (int px = 0; px < 7; ++px) {
      const float v0 = (acc[2*pr  ][2*px  ] + bb)*s + sh;
      const float v1 = (acc[2*pr  ][2*px+1] + bb)*s + sh;
      const float v2 = (acc[2*pr+1][2*px  ] + bb)*s + sh;
      const float v3 = (acc[2*pr+1][2*px+1] + bb)*s + sh;
      out[(((size_t)b*32 + co)*56 + py0+pr)*56 + px0+px] =
          fmaxf(fmaxf(fmaxf(v0, v1), fmaxf(v2, v3)), 0.f);
    }
}

// -------- conv3 (32->64) + BN + ReLU + partial mean, LDS band version -------
// grid (28, 16): band of 2 output rows (4 input rows). 256 thr = 4 x-slices
// x 64 co. Writes per-band partial sums; reduce_mean finishes.
__global__ __launch_bounds__(256) void conv3_band(
    const float* __restrict__ h2, const float* __restrict__ w,
    const float* __restrict__ cb, const float* __restrict__ g,
    const float* __restrict__ be, const float* __restrict__ mm,
    const float* __restrict__ vv, float* __restrict__ part)
{
  const int band = blockIdx.x;     // 0..27
  const int b    = blockIdx.y;     // 0..15
  const int tid  = threadIdx.x;
  const int co   = tid & 63;
  const int q    = tid >> 6;       // 0..3, x-slice
  const int y0   = band * 2;
  __shared__ float in_t[8][4][58];
  __shared__ float wt[8][9][64];
  __shared__ float red[4][64];
  float acc[2][14];
#pragma unroll
  for (int i = 0; i < 2; ++i)
#pragma unroll
    for (int j = 0; j < 14; ++j) acc[i][j] = 0.f;

  for (int chunk = 0; chunk < 4; ++chunk) {
    const int ci0 = chunk * 8;
    __syncthreads();
    for (int i = tid; i < 8*4*56; i += 256) {
      const int x = i % 56, r = (i / 56) % 4, cc = i / 224;
      const int y = y0 - 1 + r;
      float v = 0.f;
      if (y >= 0 && y < 56)
        v = h2[(((size_t)b*32 + ci0+cc)*56 + y)*56 + x];
      in_t[cc][r][x+1] = v;
    }
    if (tid < 32) { const int cc = tid >> 2, r = tid & 3;
                    in_t[cc][r][0] = 0.f; in_t[cc][r][57] = 0.f; }
    for (int i = tid; i < 8*9*64; i += 256) {
      const int coi = i & 63, k = (i >> 6) % 9, cc = i / 576;
      wt[cc][k][coi] = w[coi*288 + (ci0+cc)*9 + k];
    }
    __syncthreads();
    const int x0 = q * 14;
    for (int cc = 0; cc < 8; ++cc) {
      float wr[9];
#pragma unroll
      for (int k = 0; k < 9; ++k) wr[k] = wt[cc][k][co];
#pragma unroll
      for (int rr = 0; rr < 4; ++rr) {
        float xr[16];
        const float2* rp = (const float2*)(&in_t[cc][rr][x0]);
#pragma unroll
        for (int t = 0; t < 8; ++t) { const float2 v = rp[t]; xr[2*t] = v.x; xr[2*t+1] = v.y; }
#pragma unroll
        for (int orow = 0; orow < 2; ++orow) {
          const int krow = rr - orow;
          if (krow < 0 || krow > 2) continue;
#pragma unroll
          for (int x = 0; x < 14; ++x) {
            acc[orow][x] = fmaf(xr[x  ], wr[krow*3  ], acc[orow][x]);
            acc[orow][x] = fmaf(xr[x+1], wr[krow*3+1], acc[orow][x]);
            acc[orow][x] = fmaf(xr[x+2], wr[krow*3+2], acc[orow][x]);
          }
        }
      }
    }
  }
  const float s  = g[co] * rsqrtf(vv[co] + 1e-5f);
  const float sh = be[co] - mm[co]*s;
  const float bb = cb[co];
  float sum = 0.f;
#pragma unroll
  for (int orow = 0; orow < 2; ++orow)
#pragma unroll
    for (int x = 0; x < 14; ++x)
      sum += fmaxf((acc[orow][x] + bb)*s + sh, 0.f);
  red[q][co] = sum;
  __syncthreads();
  if (tid < 64)
    part[(((size_t)b*64 + co)*28) + band] =
        red[0][co] + red[1][co] + red[2][co] + red[3][co];
}

// -------------------- finish the global mean --------------------------------
__global__ __launch_bounds__(256) void reduce_mean(
    const float* __restrict__ part, float* __restrict__ h3)
{
  const int idx = blockIdx.x * 256 + threadIdx.x;   // b*64+co, 1024 total
  if (idx >= 1024) return;
  float s = 0.f;
#pragma unroll
  for (int bnd = 0; bnd < 28; ++bnd) s += part[(size_t)idx*28 + bnd];
  h3[idx] = s * (1.0f / 3136.0f);
}

// ----------------------------- FC + ReLU ------------------------------------
__global__ __launch_bounds__(256) void fc_relu(
    const float* __restrict__ h3, const float* __restrict__ fw,
    const float* __restrict__ fb, float* __restrict__ out)
{
  const int idx = blockIdx.x * 256 + threadIdx.x;
  if (idx >= 16*128) return;
  const int o = idx % 128, b = idx / 128;
  float acc = fb[o];
#pragma unroll
  for (int c = 0; c < 64; ++c)
    acc = fmaf(h3[b*64 + c], fw[o*64 + c], acc);
  out[idx] = fmaxf(acc, 0.f);
}

extern "C" void kernel_launch(void* const* d_in, const int* in_sizes, int n_in,
                              void* d_out, int out_size, void* d_ws, size_t ws_size,
                              hipStream_t stream) {
  const float* seq  = (const float*)d_in[0];
  const float* dcos = (const float*)d_in[1];
  const float* dsin = (const float*)d_in[2];
  const float* c1w  = (const float*)d_in[3];
  const float* c1b  = (const float*)d_in[4];
  const float* b1g  = (const float*)d_in[5];
  const float* b1b  = (const float*)d_in[6];
  const float* b1m  = (const float*)d_in[7];
  const float* b1v  = (const float*)d_in[8];
  const float* c2w  = (const float*)d_in[9];
  const float* c2b  = (const float*)d_in[10];
  const float* b2g  = (const float*)d_in[11];
  const float* b2b  = (const float*)d_in[12];
  const float* b2m  = (const float*)d_in[13];
  const float* b2v  = (const float*)d_in[14];
  const float* c3w  = (const float*)d_in[15];
  const float* c3b  = (const float*)d_in[16];
  const float* b3g  = (const float*)d_in[17];
  const float* b3b  = (const float*)d_in[18];
  const float* b3m  = (const float*)d_in[19];
  const float* b3v  = (const float*)d_in[20];
  const float* fw   = (const float*)d_in[21];
  const float* fb   = (const float*)d_in[22];
  float* out = (float*)d_out;

  float* ws   = (float*)d_ws;
  float* Cx   = ws;               // 2,408,448 floats
  float* Sx   = ws + 2408448;     // 2,408,448
  float* spec = ws + 4816896;     // 2,408,448
  float* h1   = ws;               // 3,211,264 (reuses dead Cx+Sx after dft)
  float* h2   = ws + 4816896;     // 1,605,632 (reuses dead spec after conv1)
  float* part = ws;               // 28,672 (reuses dead h1 after conv2)
  float* h3   = ws + 7225344;     // 1,024

  dim3 blk(16, 16);
  dim3 gdft(7, 7, 48);
  dft_stage1<<<gdft, blk, 0, stream>>>(seq, dcos, dsin, Cx, Sx);
  dft_stage2<<<gdft, blk, 0, stream>>>(Cx, Sx, dcos, dsin, spec);
  conv1_pool<<<12544, 256, 0, stream>>>(spec, c1w, c1b, b1g, b1b, b1m, b1v, h1);
  conv2_band<<<dim3(28, 16), 256, 0, stream>>>(h1, c2w, c2b, b2g, b2b, b2m, b2v, h2);
  conv3_band<<<dim3(28, 16), 256, 0, stream>>>(h2, c3w, c3b, b3g, b3b, b3m, b3v, part);
  reduce_mean<<<4, 256, 0, stream>>>(part, h3);
  fc_relu<<<8, 256, 0, stream>>>(h3, fw, fb, out);
}

// Round 3
// 197.894 us; speedup vs baseline: 3.3409x; 1.5516x over previous
//
#include <hip/hip_runtime.h>
#include <math.h>
#include <stddef.h>

#define N224 224
#define PIX 50176    // 224*224
#define ROWS113 25312  // 113*224, Cx/Sx rows per image

// ---------------- DFT stage 1 (half rows): Cx = C @ x, Sx = S @ x -----------
// Only rows i = 0..112 are needed (C[N-i,:] = C[i,:], S[N-i,:] = -S[i,:]).
// grid (7 k-tiles, 4 i-tiles, 48 images), block 64 = 8x8, 4x4 micro-tile.
__global__ __launch_bounds__(64) void dft1(
    const float* __restrict__ seq, const float* __restrict__ Cm,
    const float* __restrict__ Sm, float* __restrict__ Cx, float* __restrict__ Sx)
{
  const int p = blockIdx.z;
  const int b = p / 3, ch = p % 3;
  const float* __restrict__ x = seq + ((((size_t)b * 8 + 4) * 3 + ch) * PIX);
  const int i0 = blockIdx.y * 32;      // 0,32,64,96 (rows >112 masked on store)
  const int k0 = blockIdx.x * 32;
  const int tid = threadIdx.x;
  const int tx = tid & 7, ty = tid >> 3;
  // K-major layouts: [k][m], row stride 36 floats (144B, 16B-aligned)
  __shared__ float Ctt[16][36], Stt[16][36], Xt[16][36];
  float aC[4][4], aS[4][4];
#pragma unroll
  for (int a = 0; a < 4; ++a)
#pragma unroll
    for (int d = 0; d < 4; ++d) { aC[a][d] = 0.f; aS[a][d] = 0.f; }

  const int sr = tid >> 1;          // 0..31 : C/S row being transposed
  const int sk = (tid & 1) * 8;     // 0 / 8 : K sub-chunk
  const int xj = tid >> 2;          // 0..15 : x row (direct copy)
  const int xk = (tid & 3) * 8;     // 0,8,16,24

  for (int jt = 0; jt < 14; ++jt) {
    const int j = jt * 16;
    __syncthreads();
    { // X direct: Xt[jj][k]
      const float4* gp = (const float4*)(x + (size_t)(j + xj) * N224 + k0 + xk);
      const float4 v0 = gp[0], v1 = gp[1];
      *(float4*)&Xt[xj][xk]     = v0;
      *(float4*)&Xt[xj][xk + 4] = v1;
    }
    { // C,S transposed: Ctt[k][row]
      const float4* gc = (const float4*)(Cm + (size_t)(i0 + sr) * N224 + j + sk);
      const float4* gs = (const float4*)(Sm + (size_t)(i0 + sr) * N224 + j + sk);
      const float4 c0 = gc[0], c1 = gc[1];
      const float4 s0 = gs[0], s1 = gs[1];
      Ctt[sk+0][sr]=c0.x; Ctt[sk+1][sr]=c0.y; Ctt[sk+2][sr]=c0.z; Ctt[sk+3][sr]=c0.w;
      Ctt[sk+4][sr]=c1.x; Ctt[sk+5][sr]=c1.y; Ctt[sk+6][sr]=c1.z; Ctt[sk+7][sr]=c1.w;
      Stt[sk+0][sr]=s0.x; Stt[sk+1][sr]=s0.y; Stt[sk+2][sr]=s0.z; Stt[sk+3][sr]=s0.w;
      Stt[sk+4][sr]=s1.x; Stt[sk+5][sr]=s1.y; Stt[sk+6][sr]=s1.z; Stt[sk+7][sr]=s1.w;
    }
    __syncthreads();
#pragma unroll
    for (int jj = 0; jj < 16; ++jj) {
      const float4 cv4 = *(const float4*)&Ctt[jj][4*ty];
      const float4 sv4 = *(const float4*)&Stt[jj][4*ty];
      const float4 xv4 = *(const float4*)&Xt[jj][4*tx];
      const float cva[4] = {cv4.x, cv4.y, cv4.z, cv4.w};
      const float sva[4] = {sv4.x, sv4.y, sv4.z, sv4.w};
      const float xva[4] = {xv4.x, xv4.y, xv4.z, xv4.w};
#pragma unroll
      for (int a = 0; a < 4; ++a)
#pragma unroll
        for (int d = 0; d < 4; ++d) {
          aC[a][d] = fmaf(cva[a], xva[d], aC[a][d]);
          aS[a][d] = fmaf(sva[a], xva[d], aS[a][d]);
        }
    }
  }
  const size_t b113 = (size_t)p * ROWS113;
#pragma unroll
  for (int a = 0; a < 4; ++a) {
    const int i = i0 + 4*ty + a;
    if (i <= 112) {
      const size_t off = b113 + (size_t)i * N224 + k0 + 4*tx;
      *(float4*)&Cx[off] = make_float4(aC[a][0], aC[a][1], aC[a][2], aC[a][3]);
      *(float4*)&Sx[off] = make_float4(aS[a][0], aS[a][1], aS[a][2], aS[a][3]);
    }
  }
}

// --------- DFT stage 2 (half rows, mirror writes): log|X| + fftshift --------
// P1=Cx@C, P2=Sx@S, P3=Cx@S, P4=Sx@C computed for i=0..112; row i uses
// (P1-P2, P3+P4), mirror row 224-i uses (P1+P2, P3-P4).
__global__ __launch_bounds__(64) void dft2(
    const float* __restrict__ Cx, const float* __restrict__ Sx,
    const float* __restrict__ Cm, const float* __restrict__ Sm,
    float* __restrict__ spec)
{
  const int p = blockIdx.z;
  const int i0 = blockIdx.y * 32;      // 0,32,64,96
  const int k0 = blockIdx.x * 32;
  const int tid = threadIdx.x;
  const int tx = tid & 7, ty = tid >> 3;
  const size_t b113 = (size_t)p * ROWS113;
  __shared__ float CxT[16][36], SxT[16][36], Ct[16][36], St[16][36];
  float p1[4][4], p2[4][4], p3[4][4], p4[4][4];
#pragma unroll
  for (int a = 0; a < 4; ++a)
#pragma unroll
    for (int d = 0; d < 4; ++d) { p1[a][d]=0.f; p2[a][d]=0.f; p3[a][d]=0.f; p4[a][d]=0.f; }

  const int sr = tid >> 1;
  const int sk = (tid & 1) * 8;
  const int ri = (i0 + sr > 112) ? 112 : i0 + sr;   // clamp (masked on store)
  const int xj = tid >> 2;
  const int xk = (tid & 3) * 8;

  for (int jt = 0; jt < 14; ++jt) {
    const int j = jt * 16;
    __syncthreads();
    { // C,S columns direct: Ct[jj][k]
      const float4* gc = (const float4*)(Cm + (size_t)(j + xj) * N224 + k0 + xk);
      const float4* gs = (const float4*)(Sm + (size_t)(j + xj) * N224 + k0 + xk);
      const float4 c0 = gc[0], c1 = gc[1];
      const float4 s0 = gs[0], s1 = gs[1];
      *(float4*)&Ct[xj][xk]     = c0;  *(float4*)&Ct[xj][xk + 4] = c1;
      *(float4*)&St[xj][xk]     = s0;  *(float4*)&St[xj][xk + 4] = s1;
    }
    { // Cx,Sx rows transposed: CxT[k][row]
      const float4* gx = (const float4*)(Cx + b113 + (size_t)ri * N224 + j + sk);
      const float4* gy = (const float4*)(Sx + b113 + (size_t)ri * N224 + j + sk);
      const float4 c0 = gx[0], c1 = gx[1];
      const float4 s0 = gy[0], s1 = gy[1];
      CxT[sk+0][sr]=c0.x; CxT[sk+1][sr]=c0.y; CxT[sk+2][sr]=c0.z; CxT[sk+3][sr]=c0.w;
      CxT[sk+4][sr]=c1.x; CxT[sk+5][sr]=c1.y; CxT[sk+6][sr]=c1.z; CxT[sk+7][sr]=c1.w;
      SxT[sk+0][sr]=s0.x; SxT[sk+1][sr]=s0.y; SxT[sk+2][sr]=s0.z; SxT[sk+3][sr]=s0.w;
      SxT[sk+4][sr]=s1.x; SxT[sk+5][sr]=s1.y; SxT[sk+6][sr]=s1.z; SxT[sk+7][sr]=s1.w;
    }
    __syncthreads();
#pragma unroll
    for (int jj = 0; jj < 16; ++jj) {
      const float4 cx4 = *(const float4*)&CxT[jj][4*ty];
      const float4 sx4 = *(const float4*)&SxT[jj][4*ty];
      const float4 cc4 = *(const float4*)&Ct[jj][4*tx];
      const float4 ss4 = *(const float4*)&St[jj][4*tx];
      const float cxa[4] = {cx4.x, cx4.y, cx4.z, cx4.w};
      const float sxa[4] = {sx4.x, sx4.y, sx4.z, sx4.w};
      const float cca[4] = {cc4.x, cc4.y, cc4.z, cc4.w};
      const float ssa[4] = {ss4.x, ss4.y, ss4.z, ss4.w};
#pragma unroll
      for (int a = 0; a < 4; ++a)
#pragma unroll
        for (int d = 0; d < 4; ++d) {
          p1[a][d] = fmaf(cxa[a], cca[d], p1[a][d]);
          p2[a][d] = fmaf(sxa[a], ssa[d], p2[a][d]);
          p3[a][d] = fmaf(cxa[a], ssa[d], p3[a][d]);
          p4[a][d] = fmaf(sxa[a], cca[d], p4[a][d]);
        }
    }
  }
  const size_t sb = (size_t)p * PIX;
  const int kk0 = k0 + 4*tx;
  const int ok0 = (kk0 < 112) ? kk0 + 112 : kk0 - 112;  // 4-aligned, no straddle
#pragma unroll
  for (int a = 0; a < 4; ++a) {
    const int i = i0 + 4*ty + a;
    if (i > 112) continue;
    float sp1[4], sp2[4];
#pragma unroll
    for (int d = 0; d < 4; ++d) {
      const float re = p1[a][d] - p2[a][d];
      const float im = p3[a][d] + p4[a][d];
      sp1[d] = logf(sqrtf(fmaf(re, re, fmaf(im, im, 1e-8f))) + 1e-8f);
      const float re2 = p1[a][d] + p2[a][d];
      const float im2 = p3[a][d] - p4[a][d];
      sp2[d] = logf(sqrtf(fmaf(re2, re2, fmaf(im2, im2, 1e-8f))) + 1e-8f);
    }
    const int oi = (i < 112) ? i + 112 : i - 112;
    *(float4*)&spec[sb + (size_t)oi * N224 + ok0] =
        make_float4(sp1[0], sp1[1], sp1[2], sp1[3]);
    if (i >= 1 && i <= 111)
      *(float4*)&spec[sb + (size_t)(112 - i) * N224 + ok0] =
          make_float4(sp2[0], sp2[1], sp2[2], sp2[3]);
  }
}

// -------- conv1 (3->16) + BN + ReLU + 2x2 maxpool, LDS band version ---------
// grid (56, 16): band of 2 pooled rows (4 conv rows, 6 input rows).
// 256 threads = 16 x-slices x 16 co.
__global__ __launch_bounds__(256) void conv1_band(
    const float* __restrict__ spec, const float* __restrict__ w,
    const float* __restrict__ cb, const float* __restrict__ g,
    const float* __restrict__ be, const float* __restrict__ mm,
    const float* __restrict__ vv, float* __restrict__ out)
{
  const int band = blockIdx.x;     // 0..55
  const int b    = blockIdx.y;     // 0..15
  const int tid  = threadIdx.x;
  const int co   = tid & 15;
  const int q    = tid >> 4;       // 0..15, x-slice
  const int cy0  = band * 4;
  __shared__ float in_t[3][6][228];
  __shared__ float wt[3][9][16];
  for (int i = tid; i < 3*6*224; i += 256) {
    const int x = i % 224, r = (i / 224) % 6, cc = i / 1344;
    const int y = cy0 - 1 + r;
    float v = 0.f;
    if (y >= 0 && y < 224)
      v = spec[((size_t)b*3 + cc) * PIX + (size_t)y * N224 + x];
    in_t[cc][r][x+1] = v;
  }
  if (tid < 18) { const int cc = tid / 6, r = tid % 6;
                  in_t[cc][r][0] = 0.f; in_t[cc][r][225] = 0.f; }
  for (int i = tid; i < 3*9*16; i += 256) {
    const int coi = i & 15, k = (i >> 4) % 9, cc = i / 144;
    wt[cc][k][coi] = w[coi*27 + cc*9 + k];
  }
  __syncthreads();
  float acc[4][14];
#pragma unroll
  for (int i = 0; i < 4; ++i)
#pragma unroll
    for (int jx = 0; jx < 14; ++jx) acc[i][jx] = 0.f;
  const int x0 = q * 14;
#pragma unroll
  for (int cc = 0; cc < 3; ++cc) {
    float wr[9];
#pragma unroll
    for (int k = 0; k < 9; ++k) wr[k] = wt[cc][k][co];
#pragma unroll
    for (int rr = 0; rr < 6; ++rr) {
      float xr[16];
      const float2* rp = (const float2*)(&in_t[cc][rr][x0]);
#pragma unroll
      for (int t = 0; t < 8; ++t) { const float2 v = rp[t]; xr[2*t] = v.x; xr[2*t+1] = v.y; }
#pragma unroll
      for (int crow = 0; crow < 4; ++crow) {
        const int krow = rr - crow;
        if (krow < 0 || krow > 2) continue;
#pragma unroll
        for (int xx = 0; xx < 14; ++xx) {
          acc[crow][xx] = fmaf(xr[xx  ], wr[krow*3  ], acc[crow][xx]);
          acc[crow][xx] = fmaf(xr[xx+1], wr[krow*3+1], acc[crow][xx]);
          acc[crow][xx] = fmaf(xr[xx+2], wr[krow*3+2], acc[crow][xx]);
        }
      }
    }
  }
  const float s  = g[co] * rsqrtf(vv[co] + 1e-5f);
  const float sh = be[co] - mm[co]*s;
  const float bb = cb[co];
  const int py0 = band * 2, px0 = q * 7;
#pragma unroll
  for (int pr = 0; pr < 2; ++pr)
#pragma unroll
    for (int px = 0; px < 7; ++px) {
      const float v0 = (acc[2*pr  ][2*px  ] + bb)*s + sh;
      const float v1 = (acc[2*pr  ][2*px+1] + bb)*s + sh;
      const float v2 = (acc[2*pr+1][2*px  ] + bb)*s + sh;
      const float v3 = (acc[2*pr+1][2*px+1] + bb)*s + sh;
      out[(((size_t)b*16 + co)*112 + py0+pr)*112 + px0+px] =
          fmaxf(fmaxf(fmaxf(v0, v1), fmaxf(v2, v3)), 0.f);
    }
}

// -------- conv2 (16->32) + BN + ReLU + 2x2 maxpool, LDS band version --------
__global__ __launch_bounds__(256) void conv2_band(
    const float* __restrict__ h1, const float* __restrict__ w,
    const float* __restrict__ cb, const float* __restrict__ g,
    const float* __restrict__ be, const float* __restrict__ mm,
    const float* __restrict__ vv, float* __restrict__ out)
{
  const int band = blockIdx.x;     // 0..27
  const int b    = blockIdx.y;     // 0..15
  const int tid  = threadIdx.x;
  const int co   = tid & 31;
  const int q    = tid >> 5;       // 0..7, x-slice
  const int cy0  = band * 4;
  __shared__ float in_t[8][6][114];
  __shared__ float wt[8][9][32];
  float acc[4][14];
#pragma unroll
  for (int i = 0; i < 4; ++i)
#pragma unroll
    for (int jx = 0; jx < 14; ++jx) acc[i][jx] = 0.f;

  for (int chunk = 0; chunk < 2; ++chunk) {
    const int ci0 = chunk * 8;
    __syncthreads();
    for (int i = tid; i < 8*6*112; i += 256) {
      const int x = i % 112, r = (i / 112) % 6, cc = i / 672;
      const int y = cy0 - 1 + r;
      float v = 0.f;
      if (y >= 0 && y < 112)
        v = h1[(((size_t)b*16 + ci0+cc)*112 + y)*112 + x];
      in_t[cc][r][x+1] = v;
    }
    if (tid < 48) { const int cc = tid / 6, r = tid % 6;
                    in_t[cc][r][0] = 0.f; in_t[cc][r][113] = 0.f; }
    for (int i = tid; i < 8*9*32; i += 256) {
      const int coi = i & 31, k = (i >> 5) % 9, cc = i / 288;
      wt[cc][k][coi] = w[coi*144 + (ci0+cc)*9 + k];
    }
    __syncthreads();
    const int x0 = q * 14;
    for (int cc = 0; cc < 8; ++cc) {
      float wr[9];
#pragma unroll
      for (int k = 0; k < 9; ++k) wr[k] = wt[cc][k][co];
#pragma unroll
      for (int rr = 0; rr < 6; ++rr) {
        float xr[16];
        const float2* rp = (const float2*)(&in_t[cc][rr][x0]);
#pragma unroll
        for (int t = 0; t < 8; ++t) { const float2 v = rp[t]; xr[2*t] = v.x; xr[2*t+1] = v.y; }
#pragma unroll
        for (int crow = 0; crow < 4; ++crow) {
          const int krow = rr - crow;
          if (krow < 0 || krow > 2) continue;
#pragma unroll
          for (int x = 0; x < 14; ++x) {
            acc[crow][x] = fmaf(xr[x  ], wr[krow*3  ], acc[crow][x]);
            acc[crow][x] = fmaf(xr[x+1], wr[krow*3+1], acc[crow][x]);
            acc[crow][x] = fmaf(xr[x+2], wr[krow*3+2], acc[crow][x]);
          }
        }
      }
    }
  }
  const float s  = g[co] * rsqrtf(vv[co] + 1e-5f);
  const float sh = be[co] - mm[co]*s;
  const float bb = cb[co];
  const int py0 = band * 2, px0 = q * 7;
#pragma unroll
  for (int pr = 0; pr < 2; ++pr)
#pragma unroll
    for (int px = 0; px < 7; ++px) {
      const float v0 = (acc[2*pr  ][2*px  ] + bb)*s + sh;
      const float v1 = (acc[2*pr  ][2*px+1] + bb)*s + sh;
      const float v2 = (acc[2*pr+1][2*px  ] + bb)*s + sh;
      const float v3 = (acc[2*pr+1][2*px+1] + bb)*s + sh;
      out[(((size_t)b*32 + co)*56 + py0+pr)*56 + px0+px] =
          fmaxf(fmaxf(fmaxf(v0, v1), fmaxf(v2, v3)), 0.f);
    }
}

// -------- conv3 (32->64) + BN + ReLU + partial mean, LDS band version -------
__global__ __launch_bounds__(256) void conv3_band(
    const float* __restrict__ h2, const float* __restrict__ w,
    const float* __restrict__ cb, const float* __restrict__ g,
    const float* __restrict__ be, const float* __restrict__ mm,
    const float* __restrict__ vv, float* __restrict__ part)
{
  const int band = blockIdx.x;     // 0..27
  const int b    = blockIdx.y;     // 0..15
  const int tid  = threadIdx.x;
  const int co   = tid & 63;
  const int q    = tid >> 6;       // 0..3, x-slice
  const int y0   = band * 2;
  __shared__ float in_t[8][4][58];
  __shared__ float wt[8][9][64];
  __shared__ float red[4][64];
  float acc[2][14];
#pragma unroll
  for (int i = 0; i < 2; ++i)
#pragma unroll
    for (int jx = 0; jx < 14; ++jx) acc[i][jx] = 0.f;

  for (int chunk = 0; chunk < 4; ++chunk) {
    const int ci0 = chunk * 8;
    __syncthreads();
    for (int i = tid; i < 8*4*56; i += 256) {
      const int x = i % 56, r = (i / 56) % 4, cc = i / 224;
      const int y = y0 - 1 + r;
      float v = 0.f;
      if (y >= 0 && y < 56)
        v = h2[(((size_t)b*32 + ci0+cc)*56 + y)*56 + x];
      in_t[cc][r][x+1] = v;
    }
    if (tid < 32) { const int cc = tid >> 2, r = tid & 3;
                    in_t[cc][r][0] = 0.f; in_t[cc][r][57] = 0.f; }
    for (int i = tid; i < 8*9*64; i += 256) {
      const int coi = i & 63, k = (i >> 6) % 9, cc = i / 576;
      wt[cc][k][coi] = w[coi*288 + (ci0+cc)*9 + k];
    }
    __syncthreads();
    const int x0 = q * 14;
    for (int cc = 0; cc < 8; ++cc) {
      float wr[9];
#pragma unroll
      for (int k = 0; k < 9; ++k) wr[k] = wt[cc][k][co];
#pragma unroll
      for (int rr = 0; rr < 4; ++rr) {
        float xr[16];
        const float2* rp = (const float2*)(&in_t[cc][rr][x0]);
#pragma unroll
        for (int t = 0; t < 8; ++t) { const float2 v = rp[t]; xr[2*t] = v.x; xr[2*t+1] = v.y; }
#pragma unroll
        for (int orow = 0; orow < 2; ++orow) {
          const int krow = rr - orow;
          if (krow < 0 || krow > 2) continue;
#pragma unroll
          for (int x = 0; x < 14; ++x) {
            acc[orow][x] = fmaf(xr[x  ], wr[krow*3  ], acc[orow][x]);
            acc[orow][x] = fmaf(xr[x+1], wr[krow*3+1], acc[orow][x]);
            acc[orow][x] = fmaf(xr[x+2], wr[krow*3+2], acc[orow][x]);
          }
        }
      }
    }
  }
  const float s  = g[co] * rsqrtf(vv[co] + 1e-5f);
  const float sh = be[co] - mm[co]*s;
  const float bb = cb[co];
  float sum = 0.f;
#pragma unroll
  for (int orow = 0; orow < 2; ++orow)
#pragma unroll
    for (int x = 0; x < 14; ++x)
      sum += fmaxf((acc[orow][x] + bb)*s + sh, 0.f);
  red[q][co] = sum;
  __syncthreads();
  if (tid < 64)
    part[(((size_t)b*64 + co)*28) + band] =
        red[0][co] + red[1][co] + red[2][co] + red[3][co];
}

// -------------------- finish the global mean --------------------------------
__global__ __launch_bounds__(256) void reduce_mean(
    const float* __restrict__ part, float* __restrict__ h3)
{
  const int idx = blockIdx.x * 256 + threadIdx.x;   // b*64+co, 1024 total
  if (idx >= 1024) return;
  float s = 0.f;
#pragma unroll
  for (int bnd = 0; bnd < 28; ++bnd) s += part[(size_t)idx*28 + bnd];
  h3[idx] = s * (1.0f / 3136.0f);
}

// ----------------------------- FC + ReLU ------------------------------------
__global__ __launch_bounds__(256) void fc_relu(
    const float* __restrict__ h3, const float* __restrict__ fw,
    const float* __restrict__ fb, float* __restrict__ out)
{
  const int idx = blockIdx.x * 256 + threadIdx.x;
  if (idx >= 16*128) return;
  const int o = idx % 128, b = idx / 128;
  float acc = fb[o];
#pragma unroll
  for (int c = 0; c < 64; ++c)
    acc = fmaf(h3[b*64 + c], fw[o*64 + c], acc);
  out[idx] = fmaxf(acc, 0.f);
}

extern "C" void kernel_launch(void* const* d_in, const int* in_sizes, int n_in,
                              void* d_out, int out_size, void* d_ws, size_t ws_size,
                              hipStream_t stream) {
  const float* seq  = (const float*)d_in[0];
  const float* dcos = (const float*)d_in[1];
  const float* dsin = (const float*)d_in[2];
  const float* c1w  = (const float*)d_in[3];
  const float* c1b  = (const float*)d_in[4];
  const float* b1g  = (const float*)d_in[5];
  const float* b1b  = (const float*)d_in[6];
  const float* b1m  = (const float*)d_in[7];
  const float* b1v  = (const float*)d_in[8];
  const float* c2w  = (const float*)d_in[9];
  const float* c2b  = (const float*)d_in[10];
  const float* b2g  = (const float*)d_in[11];
  const float* b2b  = (const float*)d_in[12];
  const float* b2m  = (const float*)d_in[13];
  const float* b2v  = (const float*)d_in[14];
  const float* c3w  = (const float*)d_in[15];
  const float* c3b  = (const float*)d_in[16];
  const float* b3g  = (const float*)d_in[17];
  const float* b3b  = (const float*)d_in[18];
  const float* b3m  = (const float*)d_in[19];
  const float* b3v  = (const float*)d_in[20];
  const float* fw   = (const float*)d_in[21];
  const float* fb   = (const float*)d_in[22];
  float* out = (float*)d_out;

  float* ws   = (float*)d_ws;
  float* Cx   = ws;               // 48*25312 = 1,214,976 floats (113 rows)
  float* Sx   = ws + 1214976;     // 1,214,976
  float* spec = ws + 4816896;     // 2,408,448
  float* h1   = ws;               // 3,211,264 (reuses dead Cx+Sx after dft)
  float* h2   = ws + 4816896;     // 1,605,632 (reuses dead spec after conv1)
  float* part = ws;               // 28,672 (reuses dead h1 after conv2)
  float* h3   = ws + 7225344;     // 1,024

  dft1<<<dim3(7, 4, 48), 64, 0, stream>>>(seq, dcos, dsin, Cx, Sx);
  dft2<<<dim3(7, 4, 48), 64, 0, stream>>>(Cx, Sx, dcos, dsin, spec);
  conv1_band<<<dim3(56, 16), 256, 0, stream>>>(spec, c1w, c1b, b1g, b1b, b1m, b1v, h1);
  conv2_band<<<dim3(28, 16), 256, 0, stream>>>(h1, c2w, c2b, b2g, b2b, b2m, b2v, h2);
  conv3_band<<<dim3(28, 16), 256, 0, stream>>>(h2, c3w, c3b, b3g, b3b, b3m, b3v, part);
  reduce_mean<<<4, 256, 0, stream>>>(part, h3);
  fc_relu<<<8, 256, 0, stream>>>(h3, fw, fb, out);
}

// Round 4
// 197.731 us; speedup vs baseline: 3.3436x; 1.0008x over previous
//
#include <hip/hip_runtime.h>
#include <math.h>
#include <stddef.h>

#define N224 224
#define PIX 50176      // 224*224
#define ROWS113 25312  // 113*224, Cx/Sx rows per image

// ---------------- DFT stage 1 (half rows): Cx = C @ x, Sx = S @ x -----------
// Only rows i = 0..112 needed (C[N-i,:]=C[i,:], S[N-i,:]=-S[i,:]).
// grid (7 k-tiles, 4 i-tiles, 48 images), block 64 = 8x8, 4x4 micro-tile.
// Register-prefetch double buffer over the 14 K-steps.
__global__ __launch_bounds__(64) void dft1(
    const float* __restrict__ seq, const float* __restrict__ Cm,
    const float* __restrict__ Sm, float* __restrict__ Cx, float* __restrict__ Sx)
{
  const int p = blockIdx.z;
  const int b = p / 3, ch = p % 3;
  const float* __restrict__ x = seq + ((((size_t)b * 8 + 4) * 3 + ch) * PIX);
  const int i0 = blockIdx.y * 32;      // 0,32,64,96 (rows >112 masked on store)
  const int k0 = blockIdx.x * 32;
  const int tid = threadIdx.x;
  const int tx = tid & 7, ty = tid >> 3;
  __shared__ float Ctt[16][36], Stt[16][36], Xt[16][36];
  float aC[4][4], aS[4][4];
#pragma unroll
  for (int a = 0; a < 4; ++a)
#pragma unroll
    for (int d = 0; d < 4; ++d) { aC[a][d] = 0.f; aS[a][d] = 0.f; }

  const int sr = tid >> 1;          // 0..31 : C/S row being transposed
  const int sk = (tid & 1) * 8;     // 0 / 8 : K sub-chunk
  const int xj = tid >> 2;          // 0..15 : x row (direct copy)
  const int xk = (tid & 3) * 8;     // 0,8,16,24

  const float* xbase = x  + (size_t)xj * N224 + k0 + xk;
  const float* cbase = Cm + (size_t)(i0 + sr) * N224 + sk;
  const float* sbase = Sm + (size_t)(i0 + sr) * N224 + sk;

  float4 rx0 = *(const float4*)(xbase);
  float4 rx1 = *(const float4*)(xbase + 4);
  float4 rc0 = *(const float4*)(cbase);
  float4 rc1 = *(const float4*)(cbase + 4);
  float4 rs0 = *(const float4*)(sbase);
  float4 rs1 = *(const float4*)(sbase + 4);

  for (int jt = 0; jt < 14; ++jt) {
    __syncthreads();
    *(float4*)&Xt[xj][xk]     = rx0;
    *(float4*)&Xt[xj][xk + 4] = rx1;
    Ctt[sk+0][sr]=rc0.x; Ctt[sk+1][sr]=rc0.y; Ctt[sk+2][sr]=rc0.z; Ctt[sk+3][sr]=rc0.w;
    Ctt[sk+4][sr]=rc1.x; Ctt[sk+5][sr]=rc1.y; Ctt[sk+6][sr]=rc1.z; Ctt[sk+7][sr]=rc1.w;
    Stt[sk+0][sr]=rs0.x; Stt[sk+1][sr]=rs0.y; Stt[sk+2][sr]=rs0.z; Stt[sk+3][sr]=rs0.w;
    Stt[sk+4][sr]=rs1.x; Stt[sk+5][sr]=rs1.y; Stt[sk+6][sr]=rs1.z; Stt[sk+7][sr]=rs1.w;
    __syncthreads();
    if (jt < 13) {
      const int j = (jt + 1) * 16;
      rx0 = *(const float4*)(xbase + (size_t)j * N224);
      rx1 = *(const float4*)(xbase + (size_t)j * N224 + 4);
      rc0 = *(const float4*)(cbase + j);
      rc1 = *(const float4*)(cbase + j + 4);
      rs0 = *(const float4*)(sbase + j);
      rs1 = *(const float4*)(sbase + j + 4);
    }
#pragma unroll
    for (int jj = 0; jj < 16; ++jj) {
      const float4 cv4 = *(const float4*)&Ctt[jj][4*ty];
      const float4 sv4 = *(const float4*)&Stt[jj][4*ty];
      const float4 xv4 = *(const float4*)&Xt[jj][4*tx];
      const float cva[4] = {cv4.x, cv4.y, cv4.z, cv4.w};
      const float sva[4] = {sv4.x, sv4.y, sv4.z, sv4.w};
      const float xva[4] = {xv4.x, xv4.y, xv4.z, xv4.w};
#pragma unroll
      for (int a = 0; a < 4; ++a)
#pragma unroll
        for (int d = 0; d < 4; ++d) {
          aC[a][d] = fmaf(cva[a], xva[d], aC[a][d]);
          aS[a][d] = fmaf(sva[a], xva[d], aS[a][d]);
        }
    }
  }
  const size_t b113 = (size_t)p * ROWS113;
#pragma unroll
  for (int a = 0; a < 4; ++a) {
    const int i = i0 + 4*ty + a;
    if (i <= 112) {
      const size_t off = b113 + (size_t)i * N224 + k0 + 4*tx;
      *(float4*)&Cx[off] = make_float4(aC[a][0], aC[a][1], aC[a][2], aC[a][3]);
      *(float4*)&Sx[off] = make_float4(aS[a][0], aS[a][1], aS[a][2], aS[a][3]);
    }
  }
}

// --------- DFT stage 2 (half rows, mirror writes): log|X| + fftshift --------
// P1=Cx@C, P2=Sx@S, P3=Cx@S, P4=Sx@C for i=0..112; row i -> (P1-P2, P3+P4),
// mirror row 224-i -> (P1+P2, P3-P4). Register-prefetch double buffer.
__global__ __launch_bounds__(64) void dft2(
    const float* __restrict__ Cx, const float* __restrict__ Sx,
    const float* __restrict__ Cm, const float* __restrict__ Sm,
    float* __restrict__ spec)
{
  const int p = blockIdx.z;
  const int i0 = blockIdx.y * 32;      // 0,32,64,96
  const int k0 = blockIdx.x * 32;
  const int tid = threadIdx.x;
  const int tx = tid & 7, ty = tid >> 3;
  const size_t b113 = (size_t)p * ROWS113;
  __shared__ float CxT[16][36], SxT[16][36], Ct[16][36], St[16][36];
  float p1[4][4], p2[4][4], p3[4][4], p4[4][4];
#pragma unroll
  for (int a = 0; a < 4; ++a)
#pragma unroll
    for (int d = 0; d < 4; ++d) { p1[a][d]=0.f; p2[a][d]=0.f; p3[a][d]=0.f; p4[a][d]=0.f; }

  const int sr = tid >> 1;
  const int sk = (tid & 1) * 8;
  const int ri = (i0 + sr > 112) ? 112 : i0 + sr;   // clamp (masked on store)
  const int xj = tid >> 2;
  const int xk = (tid & 3) * 8;

  const float* cxb = Cx + b113 + (size_t)ri * N224 + sk;
  const float* sxb = Sx + b113 + (size_t)ri * N224 + sk;
  const float* ccb = Cm + (size_t)xj * N224 + k0 + xk;
  const float* ssb = Sm + (size_t)xj * N224 + k0 + xk;

  float4 ra0 = *(const float4*)(cxb);
  float4 ra1 = *(const float4*)(cxb + 4);
  float4 rb0 = *(const float4*)(sxb);
  float4 rb1 = *(const float4*)(sxb + 4);
  float4 rc0 = *(const float4*)(ccb);
  float4 rc1 = *(const float4*)(ccb + 4);
  float4 rd0 = *(const float4*)(ssb);
  float4 rd1 = *(const float4*)(ssb + 4);

  for (int jt = 0; jt < 14; ++jt) {
    __syncthreads();
    *(float4*)&Ct[xj][xk]     = rc0;  *(float4*)&Ct[xj][xk + 4] = rc1;
    *(float4*)&St[xj][xk]     = rd0;  *(float4*)&St[xj][xk + 4] = rd1;
    CxT[sk+0][sr]=ra0.x; CxT[sk+1][sr]=ra0.y; CxT[sk+2][sr]=ra0.z; CxT[sk+3][sr]=ra0.w;
    CxT[sk+4][sr]=ra1.x; CxT[sk+5][sr]=ra1.y; CxT[sk+6][sr]=ra1.z; CxT[sk+7][sr]=ra1.w;
    SxT[sk+0][sr]=rb0.x; SxT[sk+1][sr]=rb0.y; SxT[sk+2][sr]=rb0.z; SxT[sk+3][sr]=rb0.w;
    SxT[sk+4][sr]=rb1.x; SxT[sk+5][sr]=rb1.y; SxT[sk+6][sr]=rb1.z; SxT[sk+7][sr]=rb1.w;
    __syncthreads();
    if (jt < 13) {
      const int j = (jt + 1) * 16;
      ra0 = *(const float4*)(cxb + j);
      ra1 = *(const float4*)(cxb + j + 4);
      rb0 = *(const float4*)(sxb + j);
      rb1 = *(const float4*)(sxb + j + 4);
      rc0 = *(const float4*)(ccb + (size_t)j * N224);
      rc1 = *(const float4*)(ccb + (size_t)j * N224 + 4);
      rd0 = *(const float4*)(ssb + (size_t)j * N224);
      rd1 = *(const float4*)(ssb + (size_t)j * N224 + 4);
    }
#pragma unroll
    for (int jj = 0; jj < 16; ++jj) {
      const float4 cx4 = *(const float4*)&CxT[jj][4*ty];
      const float4 sx4 = *(const float4*)&SxT[jj][4*ty];
      const float4 cc4 = *(const float4*)&Ct[jj][4*tx];
      const float4 ss4 = *(const float4*)&St[jj][4*tx];
      const float cxa[4] = {cx4.x, cx4.y, cx4.z, cx4.w};
      const float sxa[4] = {sx4.x, sx4.y, sx4.z, sx4.w};
      const float cca[4] = {cc4.x, cc4.y, cc4.z, cc4.w};
      const float ssa[4] = {ss4.x, ss4.y, ss4.z, ss4.w};
#pragma unroll
      for (int a = 0; a < 4; ++a)
#pragma unroll
        for (int d = 0; d < 4; ++d) {
          p1[a][d] = fmaf(cxa[a], cca[d], p1[a][d]);
          p2[a][d] = fmaf(sxa[a], ssa[d], p2[a][d]);
          p3[a][d] = fmaf(cxa[a], ssa[d], p3[a][d]);
          p4[a][d] = fmaf(sxa[a], cca[d], p4[a][d]);
        }
    }
  }
  const size_t sb = (size_t)p * PIX;
  const int kk0 = k0 + 4*tx;
  const int ok0 = (kk0 < 112) ? kk0 + 112 : kk0 - 112;  // 4-aligned, no straddle
#pragma unroll
  for (int a = 0; a < 4; ++a) {
    const int i = i0 + 4*ty + a;
    if (i > 112) continue;
    float sp1[4], sp2[4];
#pragma unroll
    for (int d = 0; d < 4; ++d) {
      const float re = p1[a][d] - p2[a][d];
      const float im = p3[a][d] + p4[a][d];
      sp1[d] = logf(sqrtf(fmaf(re, re, fmaf(im, im, 1e-8f))) + 1e-8f);
      const float re2 = p1[a][d] + p2[a][d];
      const float im2 = p3[a][d] - p4[a][d];
      sp2[d] = logf(sqrtf(fmaf(re2, re2, fmaf(im2, im2, 1e-8f))) + 1e-8f);
    }
    const int oi = (i < 112) ? i + 112 : i - 112;
    *(float4*)&spec[sb + (size_t)oi * N224 + ok0] =
        make_float4(sp1[0], sp1[1], sp1[2], sp1[3]);
    if (i >= 1 && i <= 111)
      *(float4*)&spec[sb + (size_t)(112 - i) * N224 + ok0] =
          make_float4(sp2[0], sp2[1], sp2[2], sp2[3]);
  }
}

// -------- conv1 (3->16) + BN + ReLU + 2x2 maxpool, 1 pooled row per block ---
// grid (112, 16): 2 conv rows, 4 input rows. 256 thr = 16 x-slices x 16 co.
__global__ __launch_bounds__(256) void conv1_band(
    const float* __restrict__ spec, const float* __restrict__ w,
    const float* __restrict__ cb, const float* __restrict__ g,
    const float* __restrict__ be, const float* __restrict__ mm,
    const float* __restrict__ vv, float* __restrict__ out)
{
  const int band = blockIdx.x;     // 0..111  (pooled row)
  const int b    = blockIdx.y;
  const int tid  = threadIdx.x;
  const int co   = tid & 15;
  const int q    = tid >> 4;       // 0..15
  const int cy0  = band * 2;       // conv-row base
  __shared__ float in_t[3][4][228];
  __shared__ float wt[3][9][16];
  for (int i = tid; i < 3*4*224; i += 256) {
    const int x = i % 224, r = (i / 224) % 4, cc = i / 896;
    const int y = cy0 - 1 + r;
    float v = 0.f;
    if (y >= 0 && y < 224)
      v = spec[((size_t)b*3 + cc) * PIX + (size_t)y * N224 + x];
    in_t[cc][r][x+1] = v;
  }
  if (tid < 12) { const int cc = tid / 4, r = tid % 4;
                  in_t[cc][r][0] = 0.f; in_t[cc][r][225] = 0.f; }
  for (int i = tid; i < 3*9*16; i += 256) {
    const int coi = i & 15, k = (i >> 4) % 9, cc = i / 144;
    wt[cc][k][coi] = w[coi*27 + cc*9 + k];
  }
  __syncthreads();
  float acc[2][14];
#pragma unroll
  for (int i = 0; i < 2; ++i)
#pragma unroll
    for (int jx = 0; jx < 14; ++jx) acc[i][jx] = 0.f;
  const int x0 = q * 14;
#pragma unroll
  for (int cc = 0; cc < 3; ++cc) {
    float wr[9];
#pragma unroll
    for (int k = 0; k < 9; ++k) wr[k] = wt[cc][k][co];
#pragma unroll
    for (int rr = 0; rr < 4; ++rr) {
      float xr[16];
      const float2* rp = (const float2*)(&in_t[cc][rr][x0]);
#pragma unroll
      for (int t = 0; t < 8; ++t) { const float2 v = rp[t]; xr[2*t] = v.x; xr[2*t+1] = v.y; }
#pragma unroll
      for (int crow = 0; crow < 2; ++crow) {
        const int krow = rr - crow;
        if (krow < 0 || krow > 2) continue;
#pragma unroll
        for (int xx = 0; xx < 14; ++xx) {
          acc[crow][xx] = fmaf(xr[xx  ], wr[krow*3  ], acc[crow][xx]);
          acc[crow][xx] = fmaf(xr[xx+1], wr[krow*3+1], acc[crow][xx]);
          acc[crow][xx] = fmaf(xr[xx+2], wr[krow*3+2], acc[crow][xx]);
        }
      }
    }
  }
  const float s  = g[co] * rsqrtf(vv[co] + 1e-5f);
  const float sh = be[co] - mm[co]*s;
  const float bb = cb[co];
  const int px0 = q * 7;
#pragma unroll
  for (int px = 0; px < 7; ++px) {
    const float v0 = (acc[0][2*px  ] + bb)*s + sh;
    const float v1 = (acc[0][2*px+1] + bb)*s + sh;
    const float v2 = (acc[1][2*px  ] + bb)*s + sh;
    const float v3 = (acc[1][2*px+1] + bb)*s + sh;
    out[(((size_t)b*16 + co)*112 + band)*112 + px0+px] =
        fmaxf(fmaxf(fmaxf(v0, v1), fmaxf(v2, v3)), 0.f);
  }
}

// -------- conv2 (16->32) + BN + ReLU + 2x2 maxpool, 1 pooled row per block --
// grid (56, 16): 2 conv rows, 4 input rows. 256 thr = 8 x-slices x 32 co.
__global__ __launch_bounds__(256) void conv2_band(
    const float* __restrict__ h1, const float* __restrict__ w,
    const float* __restrict__ cb, const float* __restrict__ g,
    const float* __restrict__ be, const float* __restrict__ mm,
    const float* __restrict__ vv, float* __restrict__ out)
{
  const int band = blockIdx.x;     // 0..55 (pooled row)
  const int b    = blockIdx.y;
  const int tid  = threadIdx.x;
  const int co   = tid & 31;
  const int q    = tid >> 5;       // 0..7
  const int cy0  = band * 2;       // conv-row base
  __shared__ float in_t[8][4][114];
  __shared__ float wt[8][9][32];
  float acc[2][14];
#pragma unroll
  for (int i = 0; i < 2; ++i)
#pragma unroll
    for (int jx = 0; jx < 14; ++jx) acc[i][jx] = 0.f;

  for (int chunk = 0; chunk < 2; ++chunk) {
    const int ci0 = chunk * 8;
    __syncthreads();
    for (int i = tid; i < 8*4*112; i += 256) {
      const int x = i % 112, r = (i / 112) % 4, cc = i / 448;
      const int y = cy0 - 1 + r;
      float v = 0.f;
      if (y >= 0 && y < 112)
        v = h1[(((size_t)b*16 + ci0+cc)*112 + y)*112 + x];
      in_t[cc][r][x+1] = v;
    }
    if (tid < 32) { const int cc = tid >> 2, r = tid & 3;
                    in_t[cc][r][0] = 0.f; in_t[cc][r][113] = 0.f; }
    for (int i = tid; i < 8*9*32; i += 256) {
      const int coi = i & 31, k = (i >> 5) % 9, cc = i / 288;
      wt[cc][k][coi] = w[coi*144 + (ci0+cc)*9 + k];
    }
    __syncthreads();
    const int x0 = q * 14;
    for (int cc = 0; cc < 8; ++cc) {
      float wr[9];
#pragma unroll
      for (int k = 0; k < 9; ++k) wr[k] = wt[cc][k][co];
#pragma unroll
      for (int rr = 0; rr < 4; ++rr) {
        float xr[16];
        const float2* rp = (const float2*)(&in_t[cc][rr][x0]);
#pragma unroll
        for (int t = 0; t < 8; ++t) { const float2 v = rp[t]; xr[2*t] = v.x; xr[2*t+1] = v.y; }
#pragma unroll
        for (int crow = 0; crow < 2; ++crow) {
          const int krow = rr - crow;
          if (krow < 0 || krow > 2) continue;
#pragma unroll
          for (int x = 0; x < 14; ++x) {
            acc[crow][x] = fmaf(xr[x  ], wr[krow*3  ], acc[crow][x]);
            acc[crow][x] = fmaf(xr[x+1], wr[krow*3+1], acc[crow][x]);
            acc[crow][x] = fmaf(xr[x+2], wr[krow*3+2], acc[crow][x]);
          }
        }
      }
    }
  }
  const float s  = g[co] * rsqrtf(vv[co] + 1e-5f);
  const float sh = be[co] - mm[co]*s;
  const float bb = cb[co];
  const int px0 = q * 7;
#pragma unroll
  for (int px = 0; px < 7; ++px) {
    const float v0 = (acc[0][2*px  ] + bb)*s + sh;
    const float v1 = (acc[0][2*px+1] + bb)*s + sh;
    const float v2 = (acc[1][2*px  ] + bb)*s + sh;
    const float v3 = (acc[1][2*px+1] + bb)*s + sh;
    out[(((size_t)b*32 + co)*56 + band)*56 + px0+px] =
        fmaxf(fmaxf(fmaxf(v0, v1), fmaxf(v2, v3)), 0.f);
  }
}

// -------- conv3 (32->64) + BN + ReLU + partial mean, 1 output row per block -
// grid (56, 16): 3 input rows. 256 thr = 4 x-slices x 64 co.
__global__ __launch_bounds__(256) void conv3_band(
    const float* __restrict__ h2, const float* __restrict__ w,
    const float* __restrict__ cb, const float* __restrict__ g,
    const float* __restrict__ be, const float* __restrict__ mm,
    const float* __restrict__ vv, float* __restrict__ part)
{
  const int band = blockIdx.x;     // 0..55 (output row)
  const int b    = blockIdx.y;
  const int tid  = threadIdx.x;
  const int co   = tid & 63;
  const int q    = tid >> 6;       // 0..3
  const int y0   = band;
  __shared__ float in_t[8][3][58];
  __shared__ float wt[8][9][64];
  __shared__ float red[4][64];
  float acc[14];
#pragma unroll
  for (int jx = 0; jx < 14; ++jx) acc[jx] = 0.f;

  for (int chunk = 0; chunk < 4; ++chunk) {
    const int ci0 = chunk * 8;
    __syncthreads();
    for (int i = tid; i < 8*3*56; i += 256) {
      const int x = i % 56, r = (i / 56) % 3, cc = i / 168;
      const int y = y0 - 1 + r;
      float v = 0.f;
      if (y >= 0 && y < 56)
        v = h2[(((size_t)b*32 + ci0+cc)*56 + y)*56 + x];
      in_t[cc][r][x+1] = v;
    }
    if (tid < 24) { const int cc = tid / 3, r = tid % 3;
                    in_t[cc][r][0] = 0.f; in_t[cc][r][57] = 0.f; }
    for (int i = tid; i < 8*9*64; i += 256) {
      const int coi = i & 63, k = (i >> 6) % 9, cc = i / 576;
      wt[cc][k][coi] = w[coi*288 + (ci0+cc)*9 + k];
    }
    __syncthreads();
    const int x0 = q * 14;
    for (int cc = 0; cc < 8; ++cc) {
      float wr[9];
#pragma unroll
      for (int k = 0; k < 9; ++k) wr[k] = wt[cc][k][co];
#pragma unroll
      for (int rr = 0; rr < 3; ++rr) {
        float xr[16];
        const float2* rp = (const float2*)(&in_t[cc][rr][x0]);
#pragma unroll
        for (int t = 0; t < 8; ++t) { const float2 v = rp[t]; xr[2*t] = v.x; xr[2*t+1] = v.y; }
#pragma unroll
        for (int x = 0; x < 14; ++x) {
          acc[x] = fmaf(xr[x  ], wr[rr*3  ], acc[x]);
          acc[x] = fmaf(xr[x+1], wr[rr*3+1], acc[x]);
          acc[x] = fmaf(xr[x+2], wr[rr*3+2], acc[x]);
        }
      }
    }
  }
  const float s  = g[co] * rsqrtf(vv[co] + 1e-5f);
  const float sh = be[co] - mm[co]*s;
  const float bb = cb[co];
  float sum = 0.f;
#pragma unroll
  for (int x = 0; x < 14; ++x)
    sum += fmaxf((acc[x] + bb)*s + sh, 0.f);
  red[q][co] = sum;
  __syncthreads();
  if (tid < 64)
    part[(((size_t)b*64 + co)*56) + band] =
        red[0][co] + red[1][co] + red[2][co] + red[3][co];
}

// ------------- global mean (over 56 row-partials) + FC + ReLU ---------------
// grid 16 (one per batch), block 128 (one per output feature).
__global__ __launch_bounds__(128) void mean_fc(
    const float* __restrict__ part, const float* __restrict__ fw,
    const float* __restrict__ fb, float* __restrict__ out)
{
  const int b = blockIdx.x;
  const int tid = threadIdx.x;
  __shared__ float h3s[64];
  if (tid < 64) {
    float s = 0.f;
    const float* pp = part + ((size_t)b*64 + tid)*56;
#pragma unroll
    for (int i = 0; i < 56; ++i) s += pp[i];
    h3s[tid] = s * (1.0f / 3136.0f);
  }
  __syncthreads();
  float acc = fb[tid];
#pragma unroll
  for (int c = 0; c < 64; ++c)
    acc = fmaf(h3s[c], fw[tid*64 + c], acc);
  out[b*128 + tid] = fmaxf(acc, 0.f);
}

extern "C" void kernel_launch(void* const* d_in, const int* in_sizes, int n_in,
                              void* d_out, int out_size, void* d_ws, size_t ws_size,
                              hipStream_t stream) {
  const float* seq  = (const float*)d_in[0];
  const float* dcos = (const float*)d_in[1];
  const float* dsin = (const float*)d_in[2];
  const float* c1w  = (const float*)d_in[3];
  const float* c1b  = (const float*)d_in[4];
  const float* b1g  = (const float*)d_in[5];
  const float* b1b  = (const float*)d_in[6];
  const float* b1m  = (const float*)d_in[7];
  const float* b1v  = (const float*)d_in[8];
  const float* c2w  = (const float*)d_in[9];
  const float* c2b  = (const float*)d_in[10];
  const float* b2g  = (const float*)d_in[11];
  const float* b2b  = (const float*)d_in[12];
  const float* b2m  = (const float*)d_in[13];
  const float* b2v  = (const float*)d_in[14];
  const float* c3w  = (const float*)d_in[15];
  const float* c3b  = (const float*)d_in[16];
  const float* b3g  = (const float*)d_in[17];
  const float* b3b  = (const float*)d_in[18];
  const float* b3m  = (const float*)d_in[19];
  const float* b3v  = (const float*)d_in[20];
  const float* fw   = (const float*)d_in[21];
  const float* fb   = (const float*)d_in[22];
  float* out = (float*)d_out;

  float* ws   = (float*)d_ws;
  float* Cx   = ws;               // 48*25312 = 1,214,976 floats (113 rows)
  float* Sx   = ws + 1214976;     // 1,214,976
  float* spec = ws + 4816896;     // 2,408,448
  float* h1   = ws;               // 3,211,264 (reuses dead Cx+Sx after dft)
  float* h2   = ws + 4816896;     // 1,605,632 (reuses dead spec after conv1)
  float* part = ws;               // 57,344   (reuses dead h1 after conv2)

  dft1<<<dim3(7, 4, 48), 64, 0, stream>>>(seq, dcos, dsin, Cx, Sx);
  dft2<<<dim3(7, 4, 48), 64, 0, stream>>>(Cx, Sx, dcos, dsin, spec);
  conv1_band<<<dim3(112, 16), 256, 0, stream>>>(spec, c1w, c1b, b1g, b1b, b1m, b1v, h1);
  conv2_band<<<dim3(56, 16), 256, 0, stream>>>(h1, c2w, c2b, b2g, b2b, b2m, b2v, h2);
  conv3_band<<<dim3(56, 16), 256, 0, stream>>>(h2, c3w, c3b, b3g, b3b, b3m, b3v, part);
  mean_fc<<<16, 128, 0, stream>>>(part, fw, fb, out);
}